// Round 12
// baseline (356.596 us; speedup 1.0000x reference)
//
#include <hip/hip_runtime.h>
#include <hip/hip_bf16.h>
#include <hip/hip_fp8.h>

using bf16 = __hip_bfloat16;
typedef __attribute__((ext_vector_type(8))) short bf16x8;
typedef __attribute__((ext_vector_type(4))) float f32x4;
typedef __attribute__((ext_vector_type(4))) int i32x4;
typedef __attribute__((ext_vector_type(8))) int i32x8;

#define B_DIM 8
#define N_DIM 4096
#define D_DIM 768
#define BN_DIM 32768  // B*N

__device__ __forceinline__ void gload_lds16(const void* g, void* l) {
  __builtin_amdgcn_global_load_lds(
      (const __attribute__((address_space(1))) void*)g,
      (__attribute__((address_space(3))) void*)l, 16, 0, 0);
}

__device__ __forceinline__ unsigned char to_fp8(float v) {
  return __hip_fp8_e4m3(v).__x;
}

// ---------------- fused prep: blocks [0,32768): adj f32 -> fp4 (+I), rdenom.
// blocks [32768, 58496): cvt nodes->fp8, W0->fp8, Wout->bf16 (float4 jobs).
__global__ __launch_bounds__(256) void prep_all_k(
    const float* __restrict__ adj, unsigned char* __restrict__ adj_f4,
    float* __restrict__ rdenom,
    const float* __restrict__ nodes, unsigned char* __restrict__ nodes_f8,
    const float* __restrict__ W0, unsigned char* __restrict__ w0_f8,
    const float* __restrict__ Wout, bf16* __restrict__ wout_bf) {
  const int blk = blockIdx.x;
  const int t = threadIdx.x;
  if (blk < 32768) {
    const int row = blk;  // b*4096 + n
    const int n = row & (N_DIM - 1);
    const float* __restrict__ ar = adj + (size_t)row * N_DIM;
    unsigned char* __restrict__ orow = adj_f4 + (size_t)row * (N_DIM / 2);
    float s = 0.f;
#pragma unroll
    for (int j = 0; j < N_DIM; j += 1024) {
      const int c = j + t * 4;
      float4 v = *reinterpret_cast<const float4*>(ar + c);
      s += v.x + v.y + v.z + v.w;          // raw row sum (before +I)
      if (n >= c && n < c + 4) (&v.x)[n - c] += 1.0f;  // fold +I
      // e2m1 grid {0,.5,1,1.5,2}: nibble = round(v*2)
      const unsigned n0 = (unsigned)(v.x * 2.f + 0.5f);
      const unsigned n1 = (unsigned)(v.y * 2.f + 0.5f);
      const unsigned n2 = (unsigned)(v.z * 2.f + 0.5f);
      const unsigned n3 = (unsigned)(v.w * 2.f + 0.5f);
      *reinterpret_cast<unsigned short*>(orow + (c >> 1)) =
          (unsigned short)(n0 | (n1 << 4) | (n2 << 8) | (n3 << 12));
    }
#pragma unroll
    for (int off = 32; off > 0; off >>= 1) s += __shfl_down(s, off);
    __shared__ float red[4];
    const int lane = t & 63, wv = t >> 6;
    if (lane == 0) red[wv] = s;
    __syncthreads();
    if (t == 0) rdenom[row] = 1.0f / (red[0] + red[1] + red[2] + red[3] + 1.0f);
    return;
  }
  const int j = (blk - 32768) * 256 + t;  // float4 job id, < 6586368
  if (j < 6291456) {  // nodes -> fp8
    float4 v = reinterpret_cast<const float4*>(nodes)[j];
    union { unsigned char b[4]; unsigned int u; } pk;
    pk.b[0] = to_fp8(v.x); pk.b[1] = to_fp8(v.y);
    pk.b[2] = to_fp8(v.z); pk.b[3] = to_fp8(v.w);
    reinterpret_cast<unsigned int*>(nodes_f8)[j] = pk.u;
  } else if (j < 6291456 + 147456) {  // W0 -> fp8
    const int k = j - 6291456;
    float4 v = reinterpret_cast<const float4*>(W0)[k];
    union { unsigned char b[4]; unsigned int u; } pk;
    pk.b[0] = to_fp8(v.x); pk.b[1] = to_fp8(v.y);
    pk.b[2] = to_fp8(v.z); pk.b[3] = to_fp8(v.w);
    reinterpret_cast<unsigned int*>(w0_f8)[k] = pk.u;
  } else {  // Wout -> bf16
    const int k = j - 6291456 - 147456;
    float4 v = reinterpret_cast<const float4*>(Wout)[k];
    union { bf16 h[4]; uint2 u; } pk;
    pk.h[0] = __float2bfloat16(v.x); pk.h[1] = __float2bfloat16(v.y);
    pk.h[2] = __float2bfloat16(v.z); pk.h[3] = __float2bfloat16(v.w);
    reinterpret_cast<uint2*>(wout_bf)[k] = pk.u;
  }
}

// ---------------- GEMM1: fp8 MX bt-GEMM, double-buffered, counted vmcnt (R3-proven).
__global__ __launch_bounds__(256) void gemm1_f8_k(
    const unsigned char* __restrict__ A, const unsigned char* __restrict__ Bt,
    int NT, size_t lda, size_t ldb, int gx, int gy,
    const float* __restrict__ e_bias, unsigned char* __restrict__ xwt) {
  __shared__ unsigned char lds[2][32768];     // per buf: A[128][128] | B[128][128]
  const int nwg = gridDim.x;
  const int q8 = nwg >> 3;
  const int bid = blockIdx.x;
  const int wg = (bid & 7) * q8 + (bid >> 3);
  const int bx = wg % gx;          // h-panel (fast)
  const int by = (wg / gx) % gy;   // bn-panel (slow)

  const int tid = threadIdx.x;
  const int lane = tid & 63, wave = tid >> 6;
  const int wr = wave >> 1, wc = wave & 1;
  const int row0 = bx * 128, col0 = by * 128;   // rows = h, cols = bn
  const unsigned char* __restrict__ Ab = A + (size_t)row0 * lda;
  const unsigned char* __restrict__ Bb = Bt + (size_t)col0 * ldb;

  f32x4 acc[4][4];
#pragma unroll
  for (int i = 0; i < 4; ++i)
#pragma unroll
    for (int j = 0; j < 4; ++j) acc[i][j] = 0.f;

  const int l15 = lane & 15, l7 = lane & 7;
  const int kc = (lane >> 4) * 2;
  const int o0 = l15 * 128 + ((kc ^ l7) << 4);
  const int o1 = l15 * 128 + (((kc + 1) ^ l7) << 4);

#pragma unroll
  for (int it = 0; it < 4; ++it) {
    const int q = it * 256 + tid;
    const int r = q >> 3;
    const int gc = (q & 7) ^ (r & 7);
    const int lb16 = (it * 256 + wave * 64) * 16;
    gload_lds16(Ab + (size_t)r * lda + gc * 16, &lds[0][0] + lb16);
    gload_lds16(Bb + (size_t)r * ldb + gc * 16, &lds[0][16384] + lb16);
  }

  for (int t = 0; t < NT; ++t) {
    const int cur = t & 1;
    if (t != NT - 1) {
      const int kt = (t + 1) << 7;
      unsigned char* la = &lds[cur ^ 1][0];
      unsigned char* lb = &lds[cur ^ 1][16384];
#pragma unroll
      for (int it = 0; it < 4; ++it) {
        const int q = it * 256 + tid;
        const int r = q >> 3;
        const int gc = (q & 7) ^ (r & 7);
        const int lb16 = (it * 256 + wave * 64) * 16;
        gload_lds16(Ab + (size_t)r * lda + kt + gc * 16, la + lb16);
        gload_lds16(Bb + (size_t)r * ldb + kt + gc * 16, lb + lb16);
      }
      asm volatile("s_waitcnt vmcnt(8)" ::: "memory");
    } else {
      asm volatile("s_waitcnt vmcnt(0)" ::: "memory");
    }
    __builtin_amdgcn_s_barrier();
    __builtin_amdgcn_sched_barrier(0);
    const unsigned char* la = &lds[cur][0];
    const unsigned char* lb = &lds[cur][16384];
    union frag { i32x4 q[2]; i32x8 o; };
    frag bfr[4];
#pragma unroll
    for (int ni = 0; ni < 4; ++ni) {
      const unsigned char* p = lb + (wc * 64 + ni * 16) * 128;
      bfr[ni].q[0] = *reinterpret_cast<const i32x4*>(p + o0);
      bfr[ni].q[1] = *reinterpret_cast<const i32x4*>(p + o1);
    }
#pragma unroll
    for (int mi = 0; mi < 4; ++mi) {
      frag afr;
      const unsigned char* p = la + (wr * 64 + mi * 16) * 128;
      afr.q[0] = *reinterpret_cast<const i32x4*>(p + o0);
      afr.q[1] = *reinterpret_cast<const i32x4*>(p + o1);
#pragma unroll
      for (int ni = 0; ni < 4; ++ni)
        acc[mi][ni] = __builtin_amdgcn_mfma_scale_f32_16x16x128_f8f6f4(
            afr.o, bfr[ni].o, acc[mi][ni], 0, 0,
            0, 0x7F7F7F7F, 0, 0x7F7F7F7F);   // fp8 x fp8, unit scales
    }
    __builtin_amdgcn_sched_barrier(0);
    __builtin_amdgcn_s_barrier();
  }

  const int erow = wr * 64 + (lane >> 4) * 4;
  const int ecol = wc * 64 + (lane & 15);
#pragma unroll
  for (int mi = 0; mi < 4; ++mi) {
#pragma unroll
    for (int i = 0; i < 4; ++i) {
      const int h = row0 + erow + mi * 16 + i;
      const float bias = e_bias[h];
      unsigned char* __restrict__ xrow = xwt + (size_t)h * BN_DIM;
#pragma unroll
      for (int ni = 0; ni < 4; ++ni) {
        const int cn = col0 + ecol + ni * 16;
        xrow[cn] = to_fp8(acc[mi][ni][i] + bias);
      }
    }
  }
}

// ---------------- GEMM2 v6: R5 skeleton + TRIPLE buffer (depth-2 prefetch).
// A = adj fp4 (cbsz=4), B = xwt fp8. 128x128 tile, 4 waves, 16x16x128, NT=32.
// LDS 3 x 24 KB = 72 KB -> 2 blocks/CU. Stage tile t+2 during iter t;
// vmcnt(12) retires tile t's 6 loads while 12 (t+1,t+2) stay in flight.
// Tests the latency-chain hypothesis vs the dbuf 3-blk config (R5: ~105 us).
__global__ __launch_bounds__(256, 2) void gemm2_f4_k(
    const unsigned char* __restrict__ A4,   // adj_f4 [8][4096][2048 bytes]
    const unsigned char* __restrict__ B8,   // xwt fp8 [768][32768]
    const float* __restrict__ rdenom, const float* __restrict__ nodes,
    bf16* __restrict__ gout_all) {
  __shared__ unsigned char lds[3][24576];    // per buf: A 8KB | B 16KB
  const int nwg = gridDim.x;                 // 1536
  const int q8n = nwg >> 3;
  const int bid = blockIdx.x;
  const int wg = (bid & 7) * q8n + (bid >> 3);
  const int gx = D_DIM / 128;                // 6
  const int gy = N_DIM / 128;                // 32
  const int bx = wg % gx;
  const int tmp = wg / gx;
  const int by = tmp % gy;
  const int z = tmp / gy;

  const int tid = threadIdx.x;
  const int lane = tid & 63, wave = tid >> 6;
  const int wr = wave >> 1, wc = wave & 1;
  const int row0 = by * 128, col0 = bx * 128;
  const unsigned char* __restrict__ Ab = A4 + ((size_t)z * N_DIM + row0) * (N_DIM / 2);
  const unsigned char* __restrict__ Bb = B8 + (size_t)col0 * BN_DIM + (size_t)z * N_DIM;

  f32x4 acc[4][4];
#pragma unroll
  for (int i = 0; i < 4; ++i)
#pragma unroll
    for (int j = 0; j < 4; ++j) acc[i][j] = 0.f;

  const int l15 = lane & 15, l7 = lane & 7;
  const int kc = (lane >> 4) * 2;             // B logical 16B chunk base (8 per row)
  const int o0 = l15 * 128 + ((kc ^ l7) << 4);        // B swizzled read offsets
  const int o1 = l15 * 128 + (((kc + 1) ^ l7) << 4);
  const int ac = lane >> 4;                   // A logical 16B chunk (4 per 64B row)

  // ---- staging: A 2 + B 4 gloads per thread (6 per tile)
#define STAGE2(buf, kt)                                                          \
  {                                                                              \
    const int kA = (kt) << 6; /* fp4: 64 B per 128-K tile row */                 \
    const int kB = (kt) << 7;                                                    \
    _Pragma("unroll") for (int it = 0; it < 2; ++it) {                           \
      const int q = it * 256 + tid;                                              \
      const int r = q >> 2, p = q & 3;                                           \
      const int lc = (p + 4 - ((r >> 1) & 3)) & 3;                               \
      gload_lds16(Ab + (size_t)r * (N_DIM / 2) + kA + lc * 16,                   \
                  &lds[buf][0] + (it * 256 + wave * 64) * 16);                   \
    }                                                                            \
    _Pragma("unroll") for (int it = 0; it < 4; ++it) {                           \
      const int q = it * 256 + tid;                                              \
      const int r = q >> 3;                                                      \
      const int gc = (q & 7) ^ (r & 7);                                          \
      gload_lds16(Bb + (size_t)r * BN_DIM + kB + gc * 16,                        \
                  &lds[buf][8192] + (it * 256 + wave * 64) * 16);                \
    }                                                                            \
  }

  // prologue: 2 tiles in flight
  STAGE2(0, 0);
  STAGE2(1, 1);

  int cur = 0;
  for (int t = 0; t < 32; ++t) {
    if (t < 30) {
      const int nb = (cur + 2) % 3;          // buffer of tile t+2 (= buf of t-1, released)
      STAGE2(nb, t + 2);
      asm volatile("s_waitcnt vmcnt(12)" ::: "memory");  // tile t landed; t+1,t+2 in flight
    } else if (t == 30) {
      asm volatile("s_waitcnt vmcnt(6)" ::: "memory");   // tile 30 landed; 31 in flight
    } else {
      asm volatile("s_waitcnt vmcnt(0)" ::: "memory");
    }
    __builtin_amdgcn_s_barrier();
    __builtin_amdgcn_sched_barrier(0);
    const unsigned char* la = &lds[cur][0];
    const unsigned char* lb = &lds[cur][8192];
    union frag { i32x4 q[2]; i32x8 o; };
    frag bfr[4];
#pragma unroll
    for (int ni = 0; ni < 4; ++ni) {
      const unsigned char* p = lb + (wc * 64 + ni * 16) * 128;
      bfr[ni].q[0] = *reinterpret_cast<const i32x4*>(p + o0);
      bfr[ni].q[1] = *reinterpret_cast<const i32x4*>(p + o1);
    }
#pragma unroll
    for (int mi = 0; mi < 4; ++mi) {
      const int ar = wr * 64 + mi * 16 + l15;
      const int p = (ac + (ar >> 1)) & 3;
      frag afr;
      afr.q[0] = *reinterpret_cast<const i32x4*>(la + ar * 64 + (p << 4));
      afr.q[1] = i32x4{0, 0, 0, 0};
#pragma unroll
      for (int ni = 0; ni < 4; ++ni)
        acc[mi][ni] = __builtin_amdgcn_mfma_scale_f32_16x16x128_f8f6f4(
            afr.o, bfr[ni].o, acc[mi][ni], 4, 0,
            0, 0x7F7F7F7F, 0, 0x7F7F7F7F);   // A=fp4 (cbsz=4), B=fp8, unit scales
    }
    __builtin_amdgcn_sched_barrier(0);
    __builtin_amdgcn_s_barrier();            // releases buf[cur] for staging in iter t+1
    cur = (cur + 1) % 3;
  }
#undef STAGE2

  // ---- epilogue: g = relu(C * rdenom[row]) + nodes   (bf16)
  const int erow = wr * 64 + (lane >> 4) * 4;
  const int ecol = wc * 64 + (lane & 15);
  bf16* __restrict__ gout = gout_all + (size_t)z * N_DIM * D_DIM;
  const float* __restrict__ nb = nodes + (size_t)z * N_DIM * D_DIM;
  const float* __restrict__ rdz = rdenom + z * N_DIM;
#pragma unroll
  for (int mi = 0; mi < 4; ++mi) {
#pragma unroll
    for (int i = 0; i < 4; ++i) {
      const int gm = row0 + erow + mi * 16 + i;
      const float rd = rdz[gm];
      const float* __restrict__ nrow = nb + (size_t)gm * D_DIM;
      bf16* __restrict__ grow = gout + (size_t)gm * D_DIM;
#pragma unroll
      for (int ni = 0; ni < 4; ++ni) {
        const int h = col0 + ecol + ni * 16;
        const float v = fmaxf(acc[mi][ni][i] * rd, 0.f) + nrow[h];
        grow[h] = __float2bfloat16(v);
      }
    }
  }
}

// ---------------- GEMM3: bf16 dbuf, 128x128 (R5-proven geometry).
__global__ __launch_bounds__(256) void gemm3_k(
    const bf16* __restrict__ A,   // gbf [32768][768]
    const bf16* __restrict__ Bt,  // wout_bf [768][768]
    const float* __restrict__ bias, float* __restrict__ out) {
  __shared__ bf16 lds[2][2][128 * 32];
  const int nwg = gridDim.x;  // 1536
  const int q8 = nwg >> 3;
  const int bid = blockIdx.x;
  const int wg = (bid & 7) * q8 + (bid >> 3);
  const int gx = D_DIM / 128;  // 6
  const int bx = wg % gx;
  const int by = wg / gx;

  const int tid = threadIdx.x;
  const int lane = tid & 63, wave = tid >> 6;
  const int wr = wave >> 1, wc = wave & 1;
  const int row0 = by * 128, col0 = bx * 128;
  const bf16* __restrict__ Ab = A + (size_t)row0 * D_DIM;
  const bf16* __restrict__ Bb = Bt + (size_t)col0 * D_DIM;

  f32x4 acc[4][4];
#pragma unroll
  for (int i = 0; i < 4; ++i)
#pragma unroll
    for (int j = 0; j < 4; ++j) acc[i][j] = 0.f;

  const int rowA = wr * 64 + (lane & 15);
  const int rowB = wc * 64 + (lane & 15);
  const int kc = lane >> 4;

#pragma unroll
  for (int j = 0; j < 2; ++j) {
    const int c = j * 256 + tid;
    const int r = c >> 2;
    const int gc = (c & 3) ^ (r & 3);
    const size_t go = (size_t)r * D_DIM + gc * 8;
    const int lbase = (j * 256 + wave * 64) * 8;
    gload_lds16(Ab + go, &lds[0][0][0] + lbase);
    gload_lds16(Bb + go, &lds[0][1][0] + lbase);
  }

  for (int t = 0; t < 24; ++t) {
    const int cur = t & 1;
    if (t != 23) {
      const int kt = (t + 1) * 32;
      bf16* la = &lds[cur ^ 1][0][0];
      bf16* lb = &lds[cur ^ 1][1][0];
#pragma unroll
      for (int j = 0; j < 2; ++j) {
        const int c = j * 256 + tid;
        const int r = c >> 2;
        const int gc = (c & 3) ^ (r & 3);
        const size_t go = (size_t)r * D_DIM + kt + gc * 8;
        const int lbase = (j * 256 + wave * 64) * 8;
        gload_lds16(Ab + go, la + lbase);
        gload_lds16(Bb + go, lb + lbase);
      }
      asm volatile("s_waitcnt vmcnt(4)" ::: "memory");
    } else {
      asm volatile("s_waitcnt vmcnt(0)" ::: "memory");
    }
    __builtin_amdgcn_s_barrier();
    __builtin_amdgcn_sched_barrier(0);
    const bf16* la = &lds[cur][0][0];
    const bf16* lb = &lds[cur][1][0];
    bf16x8 af[4], bv[4];
#pragma unroll
    for (int mi = 0; mi < 4; ++mi) {
      const int rr = rowA + mi * 16;
      af[mi] = *reinterpret_cast<const bf16x8*>(&la[rr * 32 + ((kc ^ (rr & 3)) << 3)]);
    }
#pragma unroll
    for (int ni = 0; ni < 4; ++ni) {
      const int rr = rowB + ni * 16;
      bv[ni] = *reinterpret_cast<const bf16x8*>(&lb[rr * 32 + ((kc ^ (rr & 3)) << 3)]);
    }
#pragma unroll
    for (int mi = 0; mi < 4; ++mi)
#pragma unroll
      for (int ni = 0; ni < 4; ++ni)
        acc[mi][ni] = __builtin_amdgcn_mfma_f32_16x16x32_bf16(af[mi], bv[ni],
                                                              acc[mi][ni], 0, 0, 0);
    __builtin_amdgcn_sched_barrier(0);
    __builtin_amdgcn_s_barrier();
  }

  const int erow = wr * 64 + (lane >> 4) * 4;
  const int ecol = wc * 64 + (lane & 15);
#pragma unroll
  for (int mi = 0; mi < 4; ++mi) {
#pragma unroll
    for (int i = 0; i < 4; ++i) {
      const int gm = row0 + erow + mi * 16 + i;
#pragma unroll
      for (int ni = 0; ni < 4; ++ni) {
        const int h = col0 + ecol + ni * 16;
        out[(size_t)gm * D_DIM + h] = acc[mi][ni][i] + bias[h];
      }
    }
  }
}

extern "C" void kernel_launch(void* const* d_in, const int* in_sizes, int n_in,
                              void* d_out, int out_size, void* d_ws, size_t ws_size,
                              hipStream_t stream) {
  const float* nodes = (const float*)d_in[0];  // [8,4096,768]
  const float* adj   = (const float*)d_in[1];  // [8,4096,4096]
  const float* W0    = (const float*)d_in[2];  // [768,768]
  const float* b0    = (const float*)d_in[3];  // [768]
  const float* Wout  = (const float*)d_in[4];  // [768,768]
  const float* bout  = (const float*)d_in[5];  // [768]
  float* out = (float*)d_out;

  char* ws = (char*)d_ws;
  size_t off = 0;
  auto alloc = [&](size_t bytes) {
    void* p = ws + off;
    off += (bytes + 255) & ~(size_t)255;
    return p;
  };
  const size_t ND = (size_t)B_DIM * N_DIM;  // 32768 rows
  unsigned char* adj_f4   = (unsigned char*)alloc((size_t)B_DIM * N_DIM * N_DIM / 2);  // 64 MiB
  unsigned char* nodes_f8 = (unsigned char*)alloc(ND * D_DIM);                         // 24 MiB
  unsigned char* xwt      = (unsigned char*)alloc((size_t)D_DIM * BN_DIM);             // 24 MiB
  bf16* gbf       = (bf16*)alloc(ND * D_DIM * 2);                                      // 48 MiB
  unsigned char* w0_f8 = (unsigned char*)alloc((size_t)D_DIM * D_DIM);
  bf16* wout_bf   = (bf16*)alloc((size_t)D_DIM * D_DIM * 2);
  float* rdenom   = (float*)alloc(ND * 4);

  // 1) fused prep: adj->fp4 (+I, rdenom) + nodes/W0->fp8 + Wout->bf16
  prep_all_k<<<dim3(32768 + 25728), dim3(256), 0, stream>>>(
      adj, adj_f4, rdenom, nodes, nodes_f8, W0, w0_f8, Wout, wout_bf);

  // 2) GEMM1 (fp8): xwt[h][bn] = fp8(W0 @ nodes^T + b0)  M=768, N=32768, K=768
  gemm1_f8_k<<<dim3((BN_DIM / 128) * (D_DIM / 128)), dim3(256), 0, stream>>>(
      w0_f8, nodes_f8, /*NT=*/6, /*lda=*/D_DIM, /*ldb=*/D_DIM,
      /*gx=*/D_DIM / 128, /*gy=*/BN_DIM / 128, b0, xwt);

  // 3) GEMM2 (fp4 x fp8, triple-buffer depth-2): g = relu(((adj+I)@xW)*rdenom)+nodes
  gemm2_f4_k<<<dim3((D_DIM / 128) * (N_DIM / 128) * B_DIM), dim3(256), 0, stream>>>(
      adj_f4, xwt, rdenom, nodes, gbf);

  // 4) GEMM3 (bf16 dbuf, 128x128): out = g @ Wout^T + bout (f32)
  gemm3_k<<<dim3((D_DIM / 128) * (BN_DIM / 128)), dim3(256), 0, stream>>>(
      gbf, wout_bf, bout, out);
}

// Round 13
// 341.740 us; speedup vs baseline: 1.0435x; 1.0435x over previous
//
#include <hip/hip_runtime.h>
#include <hip/hip_bf16.h>
#include <hip/hip_fp8.h>

using bf16 = __hip_bfloat16;
typedef __attribute__((ext_vector_type(8))) short bf16x8;
typedef __attribute__((ext_vector_type(4))) float f32x4;
typedef __attribute__((ext_vector_type(4))) int i32x4;
typedef __attribute__((ext_vector_type(8))) int i32x8;

#define B_DIM 8
#define N_DIM 4096
#define D_DIM 768
#define BN_DIM 32768  // B*N

__device__ __forceinline__ void gload_lds16(const void* g, void* l) {
  __builtin_amdgcn_global_load_lds(
      (const __attribute__((address_space(1))) void*)g,
      (__attribute__((address_space(3))) void*)l, 16, 0, 0);
}

__device__ __forceinline__ unsigned char to_fp8(float v) {
  return __hip_fp8_e4m3(v).__x;
}

// ---------------- fused prep: blocks [0,32768): adj f32 -> fp4 (+I), rdenom.
// blocks [32768, 58496): cvt nodes->fp8, W0->fp8, Wout->bf16 (float4 jobs).
__global__ __launch_bounds__(256) void prep_all_k(
    const float* __restrict__ adj, unsigned char* __restrict__ adj_f4,
    float* __restrict__ rdenom,
    const float* __restrict__ nodes, unsigned char* __restrict__ nodes_f8,
    const float* __restrict__ W0, unsigned char* __restrict__ w0_f8,
    const float* __restrict__ Wout, bf16* __restrict__ wout_bf) {
  const int blk = blockIdx.x;
  const int t = threadIdx.x;
  if (blk < 32768) {
    const int row = blk;  // b*4096 + n
    const int n = row & (N_DIM - 1);
    const float* __restrict__ ar = adj + (size_t)row * N_DIM;
    unsigned char* __restrict__ orow = adj_f4 + (size_t)row * (N_DIM / 2);
    float s = 0.f;
#pragma unroll
    for (int j = 0; j < N_DIM; j += 1024) {
      const int c = j + t * 4;
      float4 v = *reinterpret_cast<const float4*>(ar + c);
      s += v.x + v.y + v.z + v.w;          // raw row sum (before +I)
      if (n >= c && n < c + 4) (&v.x)[n - c] += 1.0f;  // fold +I
      // e2m1 grid {0,.5,1,1.5,2}: nibble = round(v*2)
      const unsigned n0 = (unsigned)(v.x * 2.f + 0.5f);
      const unsigned n1 = (unsigned)(v.y * 2.f + 0.5f);
      const unsigned n2 = (unsigned)(v.z * 2.f + 0.5f);
      const unsigned n3 = (unsigned)(v.w * 2.f + 0.5f);
      *reinterpret_cast<unsigned short*>(orow + (c >> 1)) =
          (unsigned short)(n0 | (n1 << 4) | (n2 << 8) | (n3 << 12));
    }
#pragma unroll
    for (int off = 32; off > 0; off >>= 1) s += __shfl_down(s, off);
    __shared__ float red[4];
    const int lane = t & 63, wv = t >> 6;
    if (lane == 0) red[wv] = s;
    __syncthreads();
    if (t == 0) rdenom[row] = 1.0f / (red[0] + red[1] + red[2] + red[3] + 1.0f);
    return;
  }
  const int j = (blk - 32768) * 256 + t;  // float4 job id, < 6586368
  if (j < 6291456) {  // nodes -> fp8
    float4 v = reinterpret_cast<const float4*>(nodes)[j];
    union { unsigned char b[4]; unsigned int u; } pk;
    pk.b[0] = to_fp8(v.x); pk.b[1] = to_fp8(v.y);
    pk.b[2] = to_fp8(v.z); pk.b[3] = to_fp8(v.w);
    reinterpret_cast<unsigned int*>(nodes_f8)[j] = pk.u;
  } else if (j < 6291456 + 147456) {  // W0 -> fp8
    const int k = j - 6291456;
    float4 v = reinterpret_cast<const float4*>(W0)[k];
    union { unsigned char b[4]; unsigned int u; } pk;
    pk.b[0] = to_fp8(v.x); pk.b[1] = to_fp8(v.y);
    pk.b[2] = to_fp8(v.z); pk.b[3] = to_fp8(v.w);
    reinterpret_cast<unsigned int*>(w0_f8)[k] = pk.u;
  } else {  // Wout -> bf16
    const int k = j - 6291456 - 147456;
    float4 v = reinterpret_cast<const float4*>(Wout)[k];
    union { bf16 h[4]; uint2 u; } pk;
    pk.h[0] = __float2bfloat16(v.x); pk.h[1] = __float2bfloat16(v.y);
    pk.h[2] = __float2bfloat16(v.z); pk.h[3] = __float2bfloat16(v.w);
    reinterpret_cast<uint2*>(wout_bf)[k] = pk.u;
  }
}

// ---------------- GEMM1: fp8 MX bt-GEMM, double-buffered, counted vmcnt (R3-proven).
__global__ __launch_bounds__(256) void gemm1_f8_k(
    const unsigned char* __restrict__ A, const unsigned char* __restrict__ Bt,
    int NT, size_t lda, size_t ldb, int gx, int gy,
    const float* __restrict__ e_bias, unsigned char* __restrict__ xwt) {
  __shared__ unsigned char lds[2][32768];     // per buf: A[128][128] | B[128][128]
  const int nwg = gridDim.x;
  const int q8 = nwg >> 3;
  const int bid = blockIdx.x;
  const int wg = (bid & 7) * q8 + (bid >> 3);
  const int bx = wg % gx;          // h-panel (fast)
  const int by = (wg / gx) % gy;   // bn-panel (slow)

  const int tid = threadIdx.x;
  const int lane = tid & 63, wave = tid >> 6;
  const int wr = wave >> 1, wc = wave & 1;
  const int row0 = bx * 128, col0 = by * 128;   // rows = h, cols = bn
  const unsigned char* __restrict__ Ab = A + (size_t)row0 * lda;
  const unsigned char* __restrict__ Bb = Bt + (size_t)col0 * ldb;

  f32x4 acc[4][4];
#pragma unroll
  for (int i = 0; i < 4; ++i)
#pragma unroll
    for (int j = 0; j < 4; ++j) acc[i][j] = 0.f;

  const int l15 = lane & 15, l7 = lane & 7;
  const int kc = (lane >> 4) * 2;
  const int o0 = l15 * 128 + ((kc ^ l7) << 4);
  const int o1 = l15 * 128 + (((kc + 1) ^ l7) << 4);

#pragma unroll
  for (int it = 0; it < 4; ++it) {
    const int q = it * 256 + tid;
    const int r = q >> 3;
    const int gc = (q & 7) ^ (r & 7);
    const int lb16 = (it * 256 + wave * 64) * 16;
    gload_lds16(Ab + (size_t)r * lda + gc * 16, &lds[0][0] + lb16);
    gload_lds16(Bb + (size_t)r * ldb + gc * 16, &lds[0][16384] + lb16);
  }

  for (int t = 0; t < NT; ++t) {
    const int cur = t & 1;
    if (t != NT - 1) {
      const int kt = (t + 1) << 7;
      unsigned char* la = &lds[cur ^ 1][0];
      unsigned char* lb = &lds[cur ^ 1][16384];
#pragma unroll
      for (int it = 0; it < 4; ++it) {
        const int q = it * 256 + tid;
        const int r = q >> 3;
        const int gc = (q & 7) ^ (r & 7);
        const int lb16 = (it * 256 + wave * 64) * 16;
        gload_lds16(Ab + (size_t)r * lda + kt + gc * 16, la + lb16);
        gload_lds16(Bb + (size_t)r * ldb + kt + gc * 16, lb + lb16);
      }
      asm volatile("s_waitcnt vmcnt(8)" ::: "memory");
    } else {
      asm volatile("s_waitcnt vmcnt(0)" ::: "memory");
    }
    __builtin_amdgcn_s_barrier();
    __builtin_amdgcn_sched_barrier(0);
    const unsigned char* la = &lds[cur][0];
    const unsigned char* lb = &lds[cur][16384];
    union frag { i32x4 q[2]; i32x8 o; };
    frag bfr[4];
#pragma unroll
    for (int ni = 0; ni < 4; ++ni) {
      const unsigned char* p = lb + (wc * 64 + ni * 16) * 128;
      bfr[ni].q[0] = *reinterpret_cast<const i32x4*>(p + o0);
      bfr[ni].q[1] = *reinterpret_cast<const i32x4*>(p + o1);
    }
#pragma unroll
    for (int mi = 0; mi < 4; ++mi) {
      frag afr;
      const unsigned char* p = la + (wr * 64 + mi * 16) * 128;
      afr.q[0] = *reinterpret_cast<const i32x4*>(p + o0);
      afr.q[1] = *reinterpret_cast<const i32x4*>(p + o1);
#pragma unroll
      for (int ni = 0; ni < 4; ++ni)
        acc[mi][ni] = __builtin_amdgcn_mfma_scale_f32_16x16x128_f8f6f4(
            afr.o, bfr[ni].o, acc[mi][ni], 0, 0,
            0, 0x7F7F7F7F, 0, 0x7F7F7F7F);   // fp8 x fp8, unit scales
    }
    __builtin_amdgcn_sched_barrier(0);
    __builtin_amdgcn_s_barrier();
  }

  const int erow = wr * 64 + (lane >> 4) * 4;
  const int ecol = wc * 64 + (lane & 15);
#pragma unroll
  for (int mi = 0; mi < 4; ++mi) {
#pragma unroll
    for (int i = 0; i < 4; ++i) {
      const int h = row0 + erow + mi * 16 + i;
      const float bias = e_bias[h];
      unsigned char* __restrict__ xrow = xwt + (size_t)h * BN_DIM;
#pragma unroll
      for (int ni = 0; ni < 4; ++ni) {
        const int cn = col0 + ecol + ni * 16;
        xrow[cn] = to_fp8(acc[mi][ni][i] + bias);
      }
    }
  }
}

// ---------------- GEMM2 (R5-exact, verified local optimum): A = adj fp4 (cbsz=4),
// B = xwt fp8. 128x128 tile, 4 waves, wave 64x64, 16x16x128 MFMA, BK=128, NT=32.
// LDS 48 KB dbuf -> 3 blocks/CU (12 waves/CU), vmcnt(6), 2-phase skeleton.
// Axis exploration complete: R6 256-tile (-10), R7 4-phase (-6), R9 32x32x64 (-35),
// R12 triple-buffer depth-2 (-13) all regressed vs this config.
__global__ __launch_bounds__(256, 3) void gemm2_f4_k(
    const unsigned char* __restrict__ A4,   // adj_f4 [8][4096][2048 bytes]
    const unsigned char* __restrict__ B8,   // xwt fp8 [768][32768]
    const float* __restrict__ rdenom, const float* __restrict__ nodes,
    bf16* __restrict__ gout_all) {
  __shared__ unsigned char lds[2][24576];    // per buf: A 8KB | B 16KB
  const int nwg = gridDim.x;                 // 1536
  const int q8n = nwg >> 3;
  const int bid = blockIdx.x;
  const int wg = (bid & 7) * q8n + (bid >> 3);
  const int gx = D_DIM / 128;                // 6
  const int gy = N_DIM / 128;                // 32
  const int bx = wg % gx;
  const int tmp = wg / gx;
  const int by = tmp % gy;
  const int z = tmp / gy;

  const int tid = threadIdx.x;
  const int lane = tid & 63, wave = tid >> 6;
  const int wr = wave >> 1, wc = wave & 1;
  const int row0 = by * 128, col0 = bx * 128;
  const unsigned char* __restrict__ Ab = A4 + ((size_t)z * N_DIM + row0) * (N_DIM / 2);
  const unsigned char* __restrict__ Bb = B8 + (size_t)col0 * BN_DIM + (size_t)z * N_DIM;

  f32x4 acc[4][4];
#pragma unroll
  for (int i = 0; i < 4; ++i)
#pragma unroll
    for (int j = 0; j < 4; ++j) acc[i][j] = 0.f;

  const int l15 = lane & 15, l7 = lane & 7;
  const int kc = (lane >> 4) * 2;             // B logical 16B chunk base (8 per row)
  const int o0 = l15 * 128 + ((kc ^ l7) << 4);        // B swizzled read offsets
  const int o1 = l15 * 128 + (((kc + 1) ^ l7) << 4);
  const int ac = lane >> 4;                   // A logical 16B chunk (4 per 64B row)

  // ---- staging: A 2 + B 4 gloads per thread
#define STAGE2(buf, kt)                                                          \
  {                                                                              \
    const int kA = (kt) << 6; /* fp4: 64 B per 128-K tile row */                 \
    const int kB = (kt) << 7;                                                    \
    _Pragma("unroll") for (int it = 0; it < 2; ++it) {                           \
      const int q = it * 256 + tid;                                              \
      const int r = q >> 2, p = q & 3;                                           \
      const int lc = (p + 4 - ((r >> 1) & 3)) & 3;                               \
      gload_lds16(Ab + (size_t)r * (N_DIM / 2) + kA + lc * 16,                   \
                  &lds[buf][0] + (it * 256 + wave * 64) * 16);                   \
    }                                                                            \
    _Pragma("unroll") for (int it = 0; it < 4; ++it) {                           \
      const int q = it * 256 + tid;                                              \
      const int r = q >> 3;                                                      \
      const int gc = (q & 7) ^ (r & 7);                                          \
      gload_lds16(Bb + (size_t)r * BN_DIM + kB + gc * 16,                        \
                  &lds[buf][8192] + (it * 256 + wave * 64) * 16);                \
    }                                                                            \
  }

  STAGE2(0, 0);

  for (int t = 0; t < 32; ++t) {
    const int cur = t & 1;
    if (t != 31) {
      STAGE2(cur ^ 1, t + 1);
      asm volatile("s_waitcnt vmcnt(6)" ::: "memory");  // tile t landed; t+1 in flight
    } else {
      asm volatile("s_waitcnt vmcnt(0)" ::: "memory");
    }
    __builtin_amdgcn_s_barrier();
    __builtin_amdgcn_sched_barrier(0);
    const unsigned char* la = &lds[cur][0];
    const unsigned char* lb = &lds[cur][8192];
    union frag { i32x4 q[2]; i32x8 o; };
    frag bfr[4];
#pragma unroll
    for (int ni = 0; ni < 4; ++ni) {
      const unsigned char* p = lb + (wc * 64 + ni * 16) * 128;
      bfr[ni].q[0] = *reinterpret_cast<const i32x4*>(p + o0);
      bfr[ni].q[1] = *reinterpret_cast<const i32x4*>(p + o1);
    }
#pragma unroll
    for (int mi = 0; mi < 4; ++mi) {
      const int ar = wr * 64 + mi * 16 + l15;
      const int p = (ac + (ar >> 1)) & 3;
      frag afr;
      afr.q[0] = *reinterpret_cast<const i32x4*>(la + ar * 64 + (p << 4));
      afr.q[1] = i32x4{0, 0, 0, 0};
#pragma unroll
      for (int ni = 0; ni < 4; ++ni)
        acc[mi][ni] = __builtin_amdgcn_mfma_scale_f32_16x16x128_f8f6f4(
            afr.o, bfr[ni].o, acc[mi][ni], 4, 0,
            0, 0x7F7F7F7F, 0, 0x7F7F7F7F);   // A=fp4 (cbsz=4), B=fp8, unit scales
    }
    __builtin_amdgcn_sched_barrier(0);
    __builtin_amdgcn_s_barrier();
  }
#undef STAGE2

  // ---- epilogue: g = relu(C * rdenom[row]) + nodes   (bf16)
  const int erow = wr * 64 + (lane >> 4) * 4;
  const int ecol = wc * 64 + (lane & 15);
  bf16* __restrict__ gout = gout_all + (size_t)z * N_DIM * D_DIM;
  const float* __restrict__ nb = nodes + (size_t)z * N_DIM * D_DIM;
  const float* __restrict__ rdz = rdenom + z * N_DIM;
#pragma unroll
  for (int mi = 0; mi < 4; ++mi) {
#pragma unroll
    for (int i = 0; i < 4; ++i) {
      const int gm = row0 + erow + mi * 16 + i;
      const float rd = rdz[gm];
      const float* __restrict__ nrow = nb + (size_t)gm * D_DIM;
      bf16* __restrict__ grow = gout + (size_t)gm * D_DIM;
#pragma unroll
      for (int ni = 0; ni < 4; ++ni) {
        const int h = col0 + ecol + ni * 16;
        const float v = fmaxf(acc[mi][ni][i] * rd, 0.f) + nrow[h];
        grow[h] = __float2bfloat16(v);
      }
    }
  }
}

// ---------------- GEMM3: bf16 dbuf, 128x128 (R5-proven geometry).
__global__ __launch_bounds__(256) void gemm3_k(
    const bf16* __restrict__ A,   // gbf [32768][768]
    const bf16* __restrict__ Bt,  // wout_bf [768][768]
    const float* __restrict__ bias, float* __restrict__ out) {
  __shared__ bf16 lds[2][2][128 * 32];
  const int nwg = gridDim.x;  // 1536
  const int q8 = nwg >> 3;
  const int bid = blockIdx.x;
  const int wg = (bid & 7) * q8 + (bid >> 3);
  const int gx = D_DIM / 128;  // 6
  const int bx = wg % gx;
  const int by = wg / gx;

  const int tid = threadIdx.x;
  const int lane = tid & 63, wave = tid >> 6;
  const int wr = wave >> 1, wc = wave & 1;
  const int row0 = by * 128, col0 = bx * 128;
  const bf16* __restrict__ Ab = A + (size_t)row0 * D_DIM;
  const bf16* __restrict__ Bb = Bt + (size_t)col0 * D_DIM;

  f32x4 acc[4][4];
#pragma unroll
  for (int i = 0; i < 4; ++i)
#pragma unroll
    for (int j = 0; j < 4; ++j) acc[i][j] = 0.f;

  const int rowA = wr * 64 + (lane & 15);
  const int rowB = wc * 64 + (lane & 15);
  const int kc = lane >> 4;

#pragma unroll
  for (int j = 0; j < 2; ++j) {
    const int c = j * 256 + tid;
    const int r = c >> 2;
    const int gc = (c & 3) ^ (r & 3);
    const size_t go = (size_t)r * D_DIM + gc * 8;
    const int lbase = (j * 256 + wave * 64) * 8;
    gload_lds16(Ab + go, &lds[0][0][0] + lbase);
    gload_lds16(Bb + go, &lds[0][1][0] + lbase);
  }

  for (int t = 0; t < 24; ++t) {
    const int cur = t & 1;
    if (t != 23) {
      const int kt = (t + 1) * 32;
      bf16* la = &lds[cur ^ 1][0][0];
      bf16* lb = &lds[cur ^ 1][1][0];
#pragma unroll
      for (int j = 0; j < 2; ++j) {
        const int c = j * 256 + tid;
        const int r = c >> 2;
        const int gc = (c & 3) ^ (r & 3);
        const size_t go = (size_t)r * D_DIM + kt + gc * 8;
        const int lbase = (j * 256 + wave * 64) * 8;
        gload_lds16(Ab + go, la + lbase);
        gload_lds16(Bb + go, lb + lbase);
      }
      asm volatile("s_waitcnt vmcnt(4)" ::: "memory");
    } else {
      asm volatile("s_waitcnt vmcnt(0)" ::: "memory");
    }
    __builtin_amdgcn_s_barrier();
    __builtin_amdgcn_sched_barrier(0);
    const bf16* la = &lds[cur][0][0];
    const bf16* lb = &lds[cur][1][0];
    bf16x8 af[4], bv[4];
#pragma unroll
    for (int mi = 0; mi < 4; ++mi) {
      const int rr = rowA + mi * 16;
      af[mi] = *reinterpret_cast<const bf16x8*>(&la[rr * 32 + ((kc ^ (rr & 3)) << 3)]);
    }
#pragma unroll
    for (int ni = 0; ni < 4; ++ni) {
      const int rr = rowB + ni * 16;
      bv[ni] = *reinterpret_cast<const bf16x8*>(&lb[rr * 32 + ((kc ^ (rr & 3)) << 3)]);
    }
#pragma unroll
    for (int mi = 0; mi < 4; ++mi)
#pragma unroll
      for (int ni = 0; ni < 4; ++ni)
        acc[mi][ni] = __builtin_amdgcn_mfma_f32_16x16x32_bf16(af[mi], bv[ni],
                                                              acc[mi][ni], 0, 0, 0);
    __builtin_amdgcn_sched_barrier(0);
    __builtin_amdgcn_s_barrier();
  }

  const int erow = wr * 64 + (lane >> 4) * 4;
  const int ecol = wc * 64 + (lane & 15);
#pragma unroll
  for (int mi = 0; mi < 4; ++mi) {
#pragma unroll
    for (int i = 0; i < 4; ++i) {
      const int gm = row0 + erow + mi * 16 + i;
#pragma unroll
      for (int ni = 0; ni < 4; ++ni) {
        const int h = col0 + ecol + ni * 16;
        out[(size_t)gm * D_DIM + h] = acc[mi][ni][i] + bias[h];
      }
    }
  }
}

extern "C" void kernel_launch(void* const* d_in, const int* in_sizes, int n_in,
                              void* d_out, int out_size, void* d_ws, size_t ws_size,
                              hipStream_t stream) {
  const float* nodes = (const float*)d_in[0];  // [8,4096,768]
  const float* adj   = (const float*)d_in[1];  // [8,4096,4096]
  const float* W0    = (const float*)d_in[2];  // [768,768]
  const float* b0    = (const float*)d_in[3];  // [768]
  const float* Wout  = (const float*)d_in[4];  // [768,768]
  const float* bout  = (const float*)d_in[5];  // [768]
  float* out = (float*)d_out;

  char* ws = (char*)d_ws;
  size_t off = 0;
  auto alloc = [&](size_t bytes) {
    void* p = ws + off;
    off += (bytes + 255) & ~(size_t)255;
    return p;
  };
  const size_t ND = (size_t)B_DIM * N_DIM;  // 32768 rows
  unsigned char* adj_f4   = (unsigned char*)alloc((size_t)B_DIM * N_DIM * N_DIM / 2);  // 64 MiB
  unsigned char* nodes_f8 = (unsigned char*)alloc(ND * D_DIM);                         // 24 MiB
  unsigned char* xwt      = (unsigned char*)alloc((size_t)D_DIM * BN_DIM);             // 24 MiB
  bf16* gbf       = (bf16*)alloc(ND * D_DIM * 2);                                      // 48 MiB
  unsigned char* w0_f8 = (unsigned char*)alloc((size_t)D_DIM * D_DIM);
  bf16* wout_bf   = (bf16*)alloc((size_t)D_DIM * D_DIM * 2);
  float* rdenom   = (float*)alloc(ND * 4);

  // 1) fused prep: adj->fp4 (+I, rdenom) + nodes/W0->fp8 + Wout->bf16
  prep_all_k<<<dim3(32768 + 25728), dim3(256), 0, stream>>>(
      adj, adj_f4, rdenom, nodes, nodes_f8, W0, w0_f8, Wout, wout_bf);

  // 2) GEMM1 (fp8): xwt[h][bn] = fp8(W0 @ nodes^T + b0)  M=768, N=32768, K=768
  gemm1_f8_k<<<dim3((BN_DIM / 128) * (D_DIM / 128)), dim3(256), 0, stream>>>(
      w0_f8, nodes_f8, /*NT=*/6, /*lda=*/D_DIM, /*ldb=*/D_DIM,
      /*gx=*/D_DIM / 128, /*gy=*/BN_DIM / 128, b0, xwt);

  // 3) GEMM2 (R5-exact fp4 x fp8, 16x16x128, 3 blk/CU): g = relu(((adj+I)@xW)*rdenom)+nodes
  gemm2_f4_k<<<dim3((D_DIM / 128) * (N_DIM / 128) * B_DIM), dim3(256), 0, stream>>>(
      adj_f4, xwt, rdenom, nodes, gbf);

  // 4) GEMM3 (bf16 dbuf, 128x128): out = g @ Wout^T + bout (f32)
  gemm3_k<<<dim3((D_DIM / 128) * (BN_DIM / 128)), dim3(256), 0, stream>>>(
      gbf, wout_bf, bout, out);
}